// Round 1
// baseline (1358.136 us; speedup 1.0000x reference)
//
#include <hip/hip_runtime.h>
#include <math.h>

#define B_ 8
#define S_ 32
#define D_ 256
#define N_ 256
#define K_ 51
#define V_ 50257

__device__ __forceinline__ float dot4f(float4 a, float4 b){
  return a.x*b.x + a.y*b.y + a.z*b.z + a.w*b.w;
}
__device__ __forceinline__ float gelu_exact(float x){
  return 0.5f * x * (1.0f + erff(x * 0.70710678118654752440f));
}
__device__ __forceinline__ float sigmoidf_(float x){
  return 1.0f / (1.0f + expf(-x));
}

// K1: xt[t*B+b][d] = embed[ids[b,t]][d] + pos_embed[t][d]
__global__ __launch_bounds__(256) void k_embed(const int* __restrict__ ids,
    const float* __restrict__ embed, const float* __restrict__ pose,
    float* __restrict__ xt)
{
  int bx = blockIdx.x;            // t*8 + b
  int t = bx >> 3, b = bx & 7;
  int d = threadIdx.x;
  int id = ids[b * S_ + t];
  xt[(size_t)bx * D_ + d] = embed[(size_t)id * D_ + d] + pose[(size_t)t * D_ + d];
}

// K2: scores[t*B+b][n] = dot(xt[t,b], router_W[n]) + router_b[n]
__global__ __launch_bounds__(256) void k_router(const float* __restrict__ xt,
    const float* __restrict__ rW, const float* __restrict__ rb,
    float* __restrict__ scores)
{
  int bx = blockIdx.x;            // t*8 + b
  int tid = threadIdx.x;
  __shared__ float4 xs4[64];
  if (tid < 64) xs4[tid] = ((const float4*)(xt + (size_t)bx * D_))[tid];
  __syncthreads();
  float acc = rb[tid];
  const float4* wp = (const float4*)(rW + (size_t)tid * D_);
  for (int d4 = 0; d4 < 64; d4++){
    float4 w = wp[d4]; float4 x = xs4[d4];
    acc += dot4f(w, x);
  }
  scores[(size_t)bx * N_ + tid] = acc;
}

// K3: per (t,b): full bitonic sort desc (tie: low idx first), softmax over top-K,
// and for b==0 build active/member/pos for step t.
__global__ __launch_bounds__(256) void k_topk(const float* __restrict__ scores,
    float* __restrict__ wbuf, int* __restrict__ active,
    int* __restrict__ member, int* __restrict__ pos)
{
  int bx = blockIdx.x;            // t*8 + b
  int t = bx >> 3, b = bx & 7;
  int tid = threadIdx.x;
  __shared__ float sv[256];
  __shared__ int   si[256];
  __shared__ float ex[K_];
  __shared__ float exsum;
  sv[tid] = scores[(size_t)bx * N_ + tid];
  si[tid] = tid;
  for (int kk = 2; kk <= 256; kk <<= 1){
    for (int j = kk >> 1; j > 0; j >>= 1){
      __syncthreads();
      int ixj = tid ^ j;
      if (ixj > tid){
        float va = sv[tid], vb = sv[ixj];
        int   ia = si[tid], ib = si[ixj];
        bool before = (va > vb) || (va == vb && ia < ib);
        bool up = ((tid & kk) == 0);
        if (up != before){
          sv[tid] = vb; sv[ixj] = va;
          si[tid] = ib; si[ixj] = ia;
        }
      }
    }
  }
  __syncthreads();
  float vmax = sv[0];
  if (tid < K_) ex[tid] = expf(sv[tid] - vmax);
  __syncthreads();
  if (tid == 0){
    float s = 0.0f;
    for (int k = 0; k < K_; k++) s += ex[k];
    exsum = s;
  }
  __syncthreads();
  if (tid < K_) wbuf[(size_t)bx * K_ + tid] = ex[tid] / exsum;
  if (b == 0){
    member[t * N_ + tid] = 0;
    pos[t * N_ + tid] = 0;
    __syncthreads();               // uniform branch: all threads take it
    if (tid < K_){
      int nn = si[tid];
      active[t * K_ + tid] = nn;
      member[t * N_ + nn] = 1;
      pos[t * N_ + nn] = tid;
    }
  }
}

// K4: hop0. block (k, t), 128 threads; thread owns rows o=tid and o=tid+128.
// states[t,k,b,o] = gelu(h)*g[b]*w[b,k]
__global__ __launch_bounds__(128) void k_hop0(const float* __restrict__ xt,
    const float* __restrict__ fcW, const float* __restrict__ fcB,
    const float* __restrict__ gateW, const float* __restrict__ gateB,
    const float* __restrict__ wbuf, const int* __restrict__ active,
    float* __restrict__ states)
{
  int k = blockIdx.x, t = blockIdx.y;
  int tid = threadIdx.x;
  __shared__ float xs[B_ * D_];
  __shared__ float gl[B_];
  __shared__ float wl[B_];
  int n = active[t * K_ + k];
  float4* xs4 = (float4*)xs;
  const float4* xt4 = (const float4*)(xt + (size_t)t * B_ * D_);
  #pragma unroll
  for (int i = 0; i < 4; i++) xs4[tid + i * 128] = xt4[tid + i * 128];
  if (tid < B_) wl[tid] = wbuf[(size_t)(t * B_ + tid) * K_ + k];
  __syncthreads();
  // gate: wave w computes b = w*4 .. w*4+3
  {
    int wave = tid >> 6, lane = tid & 63;
    float4 gw = ((const float4*)(gateW + (size_t)n * D_))[lane];
    float accg[4];
    #pragma unroll
    for (int j = 0; j < 4; j++){
      float4 x = xs4[(wave * 4 + j) * 64 + lane];
      accg[j] = dot4f(gw, x);
    }
    for (int s2 = 1; s2 < 64; s2 <<= 1){
      #pragma unroll
      for (int j = 0; j < 4; j++) accg[j] += __shfl_xor(accg[j], s2, 64);
    }
    if (lane == 0){
      float gb = gateB[n];
      #pragma unroll
      for (int j = 0; j < 4; j++) gl[wave * 4 + j] = sigmoidf_(accg[j] + gb);
    }
  }
  __syncthreads();
  // main: h[b][o] for o in {tid, tid+128}
  float acc0[B_] = {0,0,0,0,0,0,0,0};
  float acc1[B_] = {0,0,0,0,0,0,0,0};
  const float4* w0p = (const float4*)(fcW + (size_t)n * D_ * D_ + (size_t)tid * D_);
  const float4* w1p = (const float4*)(fcW + (size_t)n * D_ * D_ + (size_t)(tid + 128) * D_);
  for (int d4 = 0; d4 < 64; d4++){
    float4 w0 = w0p[d4], w1 = w1p[d4];
    #pragma unroll
    for (int b = 0; b < B_; b++){
      float4 x = xs4[b * 64 + d4];
      acc0[b] += dot4f(w0, x);
      acc1[b] += dot4f(w1, x);
    }
  }
  float fb0 = fcB[(size_t)n * D_ + tid];
  float fb1 = fcB[(size_t)n * D_ + tid + 128];
  #pragma unroll
  for (int b = 0; b < B_; b++){
    float gwv = gl[b] * wl[b];
    float s0 = gelu_exact(acc0[b] + fb0) * gwv;
    float s1 = gelu_exact(acc1[b] + fb1) * gwv;
    size_t base = ((size_t)(t * K_ + k) * B_ + b) * D_;
    states[base + tid] = s0;
    states[base + tid + 128] = s1;
  }
}

// K5: edge pass. block (e, t), 128 threads. Early-exit if edge inactive.
__global__ __launch_bounds__(128) void k_edge(const float* __restrict__ states,
    const float* __restrict__ connW, const float* __restrict__ fcW,
    const float* __restrict__ fcB, const float* __restrict__ gateW,
    const float* __restrict__ gateB, const int* __restrict__ esrc,
    const int* __restrict__ edst, const int* __restrict__ member,
    const int* __restrict__ pos, float* __restrict__ nxt)
{
  int e = blockIdx.x, t = blockIdx.y;
  int src = esrc[e], dst = edst[e];
  if (member[t * N_ + src] == 0 || member[t * N_ + dst] == 0) return;
  int ks = pos[t * N_ + src], kd = pos[t * N_ + dst];
  int tid = threadIdx.x;
  __shared__ float xs[B_ * D_];
  __shared__ float sg[B_ * D_];
  __shared__ float gl[B_];
  float4* xs4 = (float4*)xs;
  const float4* st4 = (const float4*)(states + (size_t)(t * K_ + ks) * B_ * D_);
  #pragma unroll
  for (int i = 0; i < 4; i++) xs4[tid + i * 128] = st4[tid + i * 128];
  __syncthreads();
  // GEMM1: sig[b][o] = sum_d states_src[b][d] * connW[e][o][d]
  {
    float acc0[B_] = {0,0,0,0,0,0,0,0};
    float acc1[B_] = {0,0,0,0,0,0,0,0};
    const float4* w0p = (const float4*)(connW + (size_t)e * D_ * D_ + (size_t)tid * D_);
    const float4* w1p = (const float4*)(connW + (size_t)e * D_ * D_ + (size_t)(tid + 128) * D_);
    for (int d4 = 0; d4 < 64; d4++){
      float4 w0 = w0p[d4], w1 = w1p[d4];
      #pragma unroll
      for (int b = 0; b < B_; b++){
        float4 x = xs4[b * 64 + d4];
        acc0[b] += dot4f(w0, x);
        acc1[b] += dot4f(w1, x);
      }
    }
    #pragma unroll
    for (int b = 0; b < B_; b++){
      sg[b * D_ + tid] = acc0[b];
      sg[b * D_ + tid + 128] = acc1[b];
    }
  }
  __syncthreads();
  // gate gg[b] = sigmoid(dot(sig[b], gateW[dst]) + gateB[dst])
  {
    int wave = tid >> 6, lane = tid & 63;
    float4 gw = ((const float4*)(gateW + (size_t)dst * D_))[lane];
    const float4* sg4 = (const float4*)sg;
    float accg[4];
    #pragma unroll
    for (int j = 0; j < 4; j++){
      float4 x = sg4[(wave * 4 + j) * 64 + lane];
      accg[j] = dot4f(gw, x);
    }
    for (int s2 = 1; s2 < 64; s2 <<= 1){
      #pragma unroll
      for (int j = 0; j < 4; j++) accg[j] += __shfl_xor(accg[j], s2, 64);
    }
    if (lane == 0){
      float gb = gateB[dst];
      #pragma unroll
      for (int j = 0; j < 4; j++) gl[wave * 4 + j] = sigmoidf_(accg[j] + gb);
    }
  }
  __syncthreads();
  // GEMM2: hh = sig @ fcW[dst]^T + fcB[dst]; act = gelu(hh)*gg; atomic into nxt[t,kd]
  {
    float acc0[B_] = {0,0,0,0,0,0,0,0};
    float acc1[B_] = {0,0,0,0,0,0,0,0};
    const float4* w0p = (const float4*)(fcW + (size_t)dst * D_ * D_ + (size_t)tid * D_);
    const float4* w1p = (const float4*)(fcW + (size_t)dst * D_ * D_ + (size_t)(tid + 128) * D_);
    const float4* sg4 = (const float4*)sg;
    for (int d4 = 0; d4 < 64; d4++){
      float4 w0 = w0p[d4], w1 = w1p[d4];
      #pragma unroll
      for (int b = 0; b < B_; b++){
        float4 x = sg4[b * 64 + d4];
        acc0[b] += dot4f(w0, x);
        acc1[b] += dot4f(w1, x);
      }
    }
    float fb0 = fcB[(size_t)dst * D_ + tid];
    float fb1 = fcB[(size_t)dst * D_ + tid + 128];
    float* nx = nxt + (size_t)(t * K_ + kd) * B_ * D_;
    #pragma unroll
    for (int b = 0; b < B_; b++){
      float a0 = gelu_exact(acc0[b] + fb0) * gl[b];
      float a1 = gelu_exact(acc1[b] + fb1) * gl[b];
      atomicAdd(&nx[b * D_ + tid], a0);
      atomicAdd(&nx[b * D_ + tid + 128], a1);
    }
  }
}

// K6: combine (mean over k of states+0.5*nxt) + LayerNorm -> normed[row=b*S+t][d]
__global__ __launch_bounds__(256) void k_ln(const float* __restrict__ states,
    const float* __restrict__ nxt, const float* __restrict__ lng,
    const float* __restrict__ lnb, float* __restrict__ normed)
{
  int row = blockIdx.x;           // b*S + t
  int b = row >> 5, t = row & 31;
  int d = threadIdx.x;
  float v = 0.0f;
  for (int k = 0; k < K_; k++){
    size_t idx = ((size_t)(t * K_ + k) * B_ + b) * D_ + d;
    v += states[idx] + 0.5f * nxt[idx];
  }
  v /= 51.0f;
  __shared__ float red[256];
  red[d] = v; __syncthreads();
  for (int s = 128; s > 0; s >>= 1){ if (d < s) red[d] += red[d + s]; __syncthreads(); }
  float mu = red[0] * (1.0f / 256.0f);
  __syncthreads();
  float c = v - mu;
  red[d] = c * c; __syncthreads();
  for (int s = 128; s > 0; s >>= 1){ if (d < s) red[d] += red[d + s]; __syncthreads(); }
  float var = red[0] * (1.0f / 256.0f);
  normed[(size_t)row * D_ + d] = c * rsqrtf(var + 1e-5f) * lng[d] + lnb[d];
}

// K7: logits[row][v] = dot(normed[row], outW[v]) + outB[v]
// block: 256 threads, 2 v's/thread (v0=vb*512+tid, v1=v0+256), 64-row LDS tile.
__global__ __launch_bounds__(256) void k_logits(const float* __restrict__ normed,
    const float* __restrict__ outW, const float* __restrict__ outB,
    float* __restrict__ out)
{
  int tid = threadIdx.x;
  int vb = blockIdx.x, rb = blockIdx.y;
  int v0 = vb * 512 + tid, v1 = v0 + 256;
  int rbase = rb * 64;
  __shared__ float4 XL[64 * 64];  // 64 rows x 64 float4 (=256 floats)
  const float4* np4 = (const float4*)(normed + (size_t)rbase * D_);
  #pragma unroll
  for (int i = 0; i < 16; i++) XL[tid + i * 256] = np4[tid + i * 256];
  __syncthreads();
  float acc0[64], acc1[64];
  #pragma unroll
  for (int r = 0; r < 64; r++){ acc0[r] = 0.0f; acc1[r] = 0.0f; }
  bool g0 = v0 < V_, g1 = v1 < V_;
  const float4* w0p = (const float4*)(outW + (size_t)(g0 ? v0 : 0) * D_);
  const float4* w1p = (const float4*)(outW + (size_t)(g1 ? v1 : 0) * D_);
  for (int d4 = 0; d4 < 64; d4++){
    float4 w0 = w0p[d4], w1 = w1p[d4];
    #pragma unroll
    for (int r = 0; r < 64; r++){
      float4 x = XL[r * 64 + d4];
      acc0[r] += dot4f(w0, x);
      acc1[r] += dot4f(w1, x);
    }
  }
  if (g0){
    float ob = outB[v0];
    for (int r = 0; r < 64; r++)
      out[(size_t)(rbase + r) * V_ + v0] = acc0[r] + ob;
  }
  if (g1){
    float ob = outB[v1];
    for (int r = 0; r < 64; r++)
      out[(size_t)(rbase + r) * V_ + v1] = acc1[r] + ob;
  }
}

extern "C" void kernel_launch(void* const* d_in, const int* in_sizes, int n_in,
                              void* d_out, int out_size, void* d_ws, size_t ws_size,
                              hipStream_t stream)
{
  const int*   ids    = (const int*)d_in[0];
  const float* embed  = (const float*)d_in[1];
  const float* pose   = (const float*)d_in[2];
  const float* rW     = (const float*)d_in[3];
  const float* rb     = (const float*)d_in[4];
  const float* fcW    = (const float*)d_in[5];
  const float* fcB    = (const float*)d_in[6];
  const float* gateW  = (const float*)d_in[7];
  const float* gateB  = (const float*)d_in[8];
  const float* connW  = (const float*)d_in[9];
  const float* lng    = (const float*)d_in[10];
  const float* lnb    = (const float*)d_in[11];
  const float* outW   = (const float*)d_in[12];
  const float* outB   = (const float*)d_in[13];
  const int*   esrc   = (const int*)d_in[14];
  const int*   edst   = (const int*)d_in[15];
  int E = in_sizes[14];
  float* out = (float*)d_out;

  char* ws = (char*)d_ws;
  float* xt     = (float*)(ws + 0);          // 65536 f
  float* scores = (float*)(ws + 262144);     // 65536 f
  float* wbuf   = (float*)(ws + 524288);     // 13056 f
  int*   active = (int*)  (ws + 589824);     // 1632 i
  int*   member = (int*)  (ws + 598016);     // 8192 i
  int*   pos    = (int*)  (ws + 630784);     // 8192 i
  float* states = (float*)(ws + 663552);     // 3342336 f
  float* nxt    = (float*)(ws + 14032896);   // 3342336 f
  float* normed = (float*)(ws + 27402240);   // 65536 f

  hipMemsetAsync(nxt, 0, (size_t)3342336 * 4, stream);

  k_embed <<<dim3(S_ * B_), 256, 0, stream>>>(ids, embed, pose, xt);
  k_router<<<dim3(S_ * B_), 256, 0, stream>>>(xt, rW, rb, scores);
  k_topk  <<<dim3(S_ * B_), 256, 0, stream>>>(scores, wbuf, active, member, pos);
  k_hop0  <<<dim3(K_, S_), 128, 0, stream>>>(xt, fcW, fcB, gateW, gateB, wbuf, active, states);
  k_edge  <<<dim3(E, S_), 128, 0, stream>>>(states, connW, fcW, fcB, gateW, gateB,
                                            esrc, edst, member, pos, nxt);
  k_ln    <<<dim3(B_ * S_), 256, 0, stream>>>(states, nxt, lng, lnb, normed);
  k_logits<<<dim3((V_ + 511) / 512, 4), 256, 0, stream>>>(normed, outW, outB, out);
}

// Round 2
// 1055.612 us; speedup vs baseline: 1.2866x; 1.2866x over previous
//
#include <hip/hip_runtime.h>
#include <math.h>

#define B_ 8
#define S_ 32
#define D_ 256
#define N_ 256
#define K_ 51
#define V_ 50257

__device__ __forceinline__ float dot4f(float4 a, float4 b){
  return a.x*b.x + a.y*b.y + a.z*b.z + a.w*b.w;
}
__device__ __forceinline__ float gelu_exact(float x){
  return 0.5f * x * (1.0f + erff(x * 0.70710678118654752440f));
}
__device__ __forceinline__ float sigmoidf_(float x){
  return 1.0f / (1.0f + expf(-x));
}

// K1: xt[t*B+b][d] = embed[ids[b,t]][d] + pos_embed[t][d]
__global__ __launch_bounds__(256) void k_embed(const int* __restrict__ ids,
    const float* __restrict__ embed, const float* __restrict__ pose,
    float* __restrict__ xt)
{
  int bx = blockIdx.x;            // t*8 + b
  int t = bx >> 3, b = bx & 7;
  int d = threadIdx.x;
  int id = ids[b * S_ + t];
  xt[(size_t)bx * D_ + d] = embed[(size_t)id * D_ + d] + pose[(size_t)t * D_ + d];
}

// K2: scores[t*B+b][n] = dot(xt[t,b], router_W[n]) + router_b[n]
__global__ __launch_bounds__(256) void k_router(const float* __restrict__ xt,
    const float* __restrict__ rW, const float* __restrict__ rb,
    float* __restrict__ scores)
{
  int bx = blockIdx.x;            // t*8 + b
  int tid = threadIdx.x;
  __shared__ float4 xs4[64];
  if (tid < 64) xs4[tid] = ((const float4*)(xt + (size_t)bx * D_))[tid];
  __syncthreads();
  float acc = rb[tid];
  const float4* wp = (const float4*)(rW + (size_t)tid * D_);
  for (int d4 = 0; d4 < 64; d4++){
    float4 w = wp[d4]; float4 x = xs4[d4];
    acc += dot4f(w, x);
  }
  scores[(size_t)bx * N_ + tid] = acc;
}

// K3: per (t,b): full bitonic sort desc (tie: low idx first), softmax over top-K,
// and for b==0 build active/member/pos for step t.
__global__ __launch_bounds__(256) void k_topk(const float* __restrict__ scores,
    float* __restrict__ wbuf, int* __restrict__ active,
    int* __restrict__ member, int* __restrict__ pos)
{
  int bx = blockIdx.x;            // t*8 + b
  int t = bx >> 3, b = bx & 7;
  int tid = threadIdx.x;
  __shared__ float sv[256];
  __shared__ int   si[256];
  __shared__ float ex[K_];
  __shared__ float exsum;
  sv[tid] = scores[(size_t)bx * N_ + tid];
  si[tid] = tid;
  for (int kk = 2; kk <= 256; kk <<= 1){
    for (int j = kk >> 1; j > 0; j >>= 1){
      __syncthreads();
      int ixj = tid ^ j;
      if (ixj > tid){
        float va = sv[tid], vb = sv[ixj];
        int   ia = si[tid], ib = si[ixj];
        bool before = (va > vb) || (va == vb && ia < ib);
        bool up = ((tid & kk) == 0);
        if (up != before){
          sv[tid] = vb; sv[ixj] = va;
          si[tid] = ib; si[ixj] = ia;
        }
      }
    }
  }
  __syncthreads();
  float vmax = sv[0];
  if (tid < K_) ex[tid] = expf(sv[tid] - vmax);
  __syncthreads();
  if (tid == 0){
    float s = 0.0f;
    for (int k = 0; k < K_; k++) s += ex[k];
    exsum = s;
  }
  __syncthreads();
  if (tid < K_) wbuf[(size_t)bx * K_ + tid] = ex[tid] / exsum;
  if (b == 0){
    member[t * N_ + tid] = 0;
    pos[t * N_ + tid] = 0;
    __syncthreads();               // uniform branch within block
    if (tid < K_){
      int nn = si[tid];
      active[t * K_ + tid] = nn;
      member[t * N_ + nn] = 1;
      pos[t * N_ + nn] = tid;
    }
  }
}

// K3b: compact active (e,t) pairs into a worklist.
__global__ __launch_bounds__(256) void k_compact(const int* __restrict__ esrc,
    const int* __restrict__ edst, const int* __restrict__ member,
    int E, int* __restrict__ count, unsigned int* __restrict__ items)
{
  int idx = blockIdx.x * 256 + threadIdx.x;
  if (idx >= E * S_) return;
  int e = idx % E, t = idx / E;
  int src = esrc[e], dst = edst[e];
  if (member[t * N_ + src] && member[t * N_ + dst]){
    int slot = atomicAdd(count, 1);
    items[slot] = ((unsigned int)t << 16) | (unsigned int)e;
  }
}

// K4: hop0. block (k, t), 256 threads; thread owns row o=tid.
// states[t,k,b,o] = gelu(h)*g[b]*w[b,k]
__global__ __launch_bounds__(256) void k_hop0(const float* __restrict__ xt,
    const float* __restrict__ fcW, const float* __restrict__ fcB,
    const float* __restrict__ gateW, const float* __restrict__ gateB,
    const float* __restrict__ wbuf, const int* __restrict__ active,
    float* __restrict__ states)
{
  int k = blockIdx.x, t = blockIdx.y;
  int tid = threadIdx.x;
  __shared__ float xs[B_ * D_];
  __shared__ float gl[B_];
  __shared__ float wl[B_];
  int n = active[t * K_ + k];
  float4* xs4 = (float4*)xs;
  const float4* xt4 = (const float4*)(xt + (size_t)t * B_ * D_);
  #pragma unroll
  for (int i = 0; i < 2; i++) xs4[tid + i * 256] = xt4[tid + i * 256];
  if (tid < B_) wl[tid] = wbuf[(size_t)(t * B_ + tid) * K_ + k];
  __syncthreads();
  // gate: wave w computes b = 2w, 2w+1
  {
    int wave = tid >> 6, lane = tid & 63;
    float4 gw = ((const float4*)(gateW + (size_t)n * D_))[lane];
    float a0 = dot4f(gw, xs4[(wave * 2 + 0) * 64 + lane]);
    float a1 = dot4f(gw, xs4[(wave * 2 + 1) * 64 + lane]);
    for (int s2 = 1; s2 < 64; s2 <<= 1){
      a0 += __shfl_xor(a0, s2, 64);
      a1 += __shfl_xor(a1, s2, 64);
    }
    if (lane == 0){
      float gb = gateB[n];
      gl[wave * 2 + 0] = sigmoidf_(a0 + gb);
      gl[wave * 2 + 1] = sigmoidf_(a1 + gb);
    }
  }
  __syncthreads();
  // main: h[b][o] for o = tid
  float acc[B_] = {0,0,0,0,0,0,0,0};
  const float4* wp = (const float4*)(fcW + (size_t)n * D_ * D_ + (size_t)tid * D_);
  for (int d4 = 0; d4 < 64; d4++){
    float4 w = wp[d4];
    #pragma unroll
    for (int b = 0; b < B_; b++) acc[b] += dot4f(w, xs4[b * 64 + d4]);
  }
  float fb = fcB[(size_t)n * D_ + tid];
  #pragma unroll
  for (int b = 0; b < B_; b++){
    float s = gelu_exact(acc[b] + fb) * gl[b] * wl[b];
    states[((size_t)(t * K_ + k) * B_ + b) * D_ + tid] = s;
  }
}

// K5: edge pass over compacted worklist. 256 threads, grid-stride over items.
__global__ __launch_bounds__(256) void k_edge2(const float* __restrict__ states,
    const float* __restrict__ connW, const float* __restrict__ fcW,
    const float* __restrict__ fcB, const float* __restrict__ gateW,
    const float* __restrict__ gateB, const int* __restrict__ esrc,
    const int* __restrict__ edst, const int* __restrict__ pos,
    const int* __restrict__ count, const unsigned int* __restrict__ items,
    float* __restrict__ nxt)
{
  __shared__ float xs[B_ * D_];
  __shared__ float sg[B_ * D_];
  __shared__ float gl[B_];
  int n_items = *count;
  int tid = threadIdx.x;
  float4* xs4 = (float4*)xs;
  float4* sg4 = (float4*)sg;
  for (int it = blockIdx.x; it < n_items; it += gridDim.x){
    unsigned int pk = items[it];
    int t = (int)(pk >> 16), e = (int)(pk & 0xFFFFu);
    int src = esrc[e], dst = edst[e];
    int ks = pos[t * N_ + src], kd = pos[t * N_ + dst];
    const float4* st4 = (const float4*)(states + (size_t)(t * K_ + ks) * B_ * D_);
    #pragma unroll
    for (int i = 0; i < 2; i++) xs4[tid + i * 256] = st4[tid + i * 256];
    __syncthreads();
    // GEMM1: sig[b][o] for o = tid
    {
      float acc[B_] = {0,0,0,0,0,0,0,0};
      const float4* wp = (const float4*)(connW + (size_t)e * D_ * D_ + (size_t)tid * D_);
      for (int d4 = 0; d4 < 64; d4++){
        float4 w = wp[d4];
        #pragma unroll
        for (int b = 0; b < B_; b++) acc[b] += dot4f(w, xs4[b * 64 + d4]);
      }
      #pragma unroll
      for (int b = 0; b < B_; b++) sg[b * D_ + tid] = acc[b];
    }
    __syncthreads();
    // gate gg[b] = sigmoid(dot(sig[b], gateW[dst]) + gateB[dst])
    {
      int wave = tid >> 6, lane = tid & 63;
      float4 gw = ((const float4*)(gateW + (size_t)dst * D_))[lane];
      float a0 = dot4f(gw, sg4[(wave * 2 + 0) * 64 + lane]);
      float a1 = dot4f(gw, sg4[(wave * 2 + 1) * 64 + lane]);
      for (int s2 = 1; s2 < 64; s2 <<= 1){
        a0 += __shfl_xor(a0, s2, 64);
        a1 += __shfl_xor(a1, s2, 64);
      }
      if (lane == 0){
        float gb = gateB[dst];
        gl[wave * 2 + 0] = sigmoidf_(a0 + gb);
        gl[wave * 2 + 1] = sigmoidf_(a1 + gb);
      }
    }
    __syncthreads();
    // GEMM2: hh[b][o] for o = tid; act -> atomic into nxt[t,kd]
    {
      float acc[B_] = {0,0,0,0,0,0,0,0};
      const float4* wp = (const float4*)(fcW + (size_t)dst * D_ * D_ + (size_t)tid * D_);
      for (int d4 = 0; d4 < 64; d4++){
        float4 w = wp[d4];
        #pragma unroll
        for (int b = 0; b < B_; b++) acc[b] += dot4f(w, sg4[b * 64 + d4]);
      }
      float fb = fcB[(size_t)dst * D_ + tid];
      float* nx = nxt + (size_t)(t * K_ + kd) * B_ * D_;
      #pragma unroll
      for (int b = 0; b < B_; b++){
        float a = gelu_exact(acc[b] + fb) * gl[b];
        atomicAdd(&nx[b * D_ + tid], a);
      }
    }
    __syncthreads();   // protect xs/sg before next iteration overwrites
  }
}

// K6: combine (mean over k of states+0.5*nxt) + LayerNorm -> normed[row=b*S+t][d]
__global__ __launch_bounds__(256) void k_ln(const float* __restrict__ states,
    const float* __restrict__ nxt, const float* __restrict__ lng,
    const float* __restrict__ lnb, float* __restrict__ normed)
{
  int row = blockIdx.x;           // b*S + t
  int b = row >> 5, t = row & 31;
  int d = threadIdx.x;
  float v = 0.0f;
  for (int k = 0; k < K_; k++){
    size_t idx = ((size_t)(t * K_ + k) * B_ + b) * D_ + d;
    v += states[idx] + 0.5f * nxt[idx];
  }
  v /= 51.0f;
  __shared__ float red[256];
  red[d] = v; __syncthreads();
  for (int s = 128; s > 0; s >>= 1){ if (d < s) red[d] += red[d + s]; __syncthreads(); }
  float mu = red[0] * (1.0f / 256.0f);
  __syncthreads();
  float c = v - mu;
  red[d] = c * c; __syncthreads();
  for (int s = 128; s > 0; s >>= 1){ if (d < s) red[d] += red[d + s]; __syncthreads(); }
  float var = red[0] * (1.0f / 256.0f);
  normed[(size_t)row * D_ + d] = c * rsqrtf(var + 1e-5f) * lng[d] + lnb[d];
}

// K7: logits[row][v] = dot(normed[row], outW[v]) + outB[v]
__global__ __launch_bounds__(256) void k_logits(const float* __restrict__ normed,
    const float* __restrict__ outW, const float* __restrict__ outB,
    float* __restrict__ out)
{
  int tid = threadIdx.x;
  int vb = blockIdx.x, rb = blockIdx.y;
  int v0 = vb * 512 + tid, v1 = v0 + 256;
  int rbase = rb * 64;
  __shared__ float4 XL[64 * 64];  // 64 rows x 64 float4 (=256 floats)
  const float4* np4 = (const float4*)(normed + (size_t)rbase * D_);
  #pragma unroll
  for (int i = 0; i < 16; i++) XL[tid + i * 256] = np4[tid + i * 256];
  __syncthreads();
  float acc0[64], acc1[64];
  #pragma unroll
  for (int r = 0; r < 64; r++){ acc0[r] = 0.0f; acc1[r] = 0.0f; }
  bool g0 = v0 < V_, g1 = v1 < V_;
  const float4* w0p = (const float4*)(outW + (size_t)(g0 ? v0 : 0) * D_);
  const float4* w1p = (const float4*)(outW + (size_t)(g1 ? v1 : 0) * D_);
  for (int d4 = 0; d4 < 64; d4++){
    float4 w0 = w0p[d4], w1 = w1p[d4];
    #pragma unroll
    for (int r = 0; r < 64; r++){
      float4 x = XL[r * 64 + d4];
      acc0[r] += dot4f(w0, x);
      acc1[r] += dot4f(w1, x);
    }
  }
  if (g0){
    float ob = outB[v0];
    for (int r = 0; r < 64; r++)
      out[(size_t)(rbase + r) * V_ + v0] = acc0[r] + ob;
  }
  if (g1){
    float ob = outB[v1];
    for (int r = 0; r < 64; r++)
      out[(size_t)(rbase + r) * V_ + v1] = acc1[r] + ob;
  }
}

extern "C" void kernel_launch(void* const* d_in, const int* in_sizes, int n_in,
                              void* d_out, int out_size, void* d_ws, size_t ws_size,
                              hipStream_t stream)
{
  const int*   ids    = (const int*)d_in[0];
  const float* embed  = (const float*)d_in[1];
  const float* pose   = (const float*)d_in[2];
  const float* rW     = (const float*)d_in[3];
  const float* rb     = (const float*)d_in[4];
  const float* fcW    = (const float*)d_in[5];
  const float* fcB    = (const float*)d_in[6];
  const float* gateW  = (const float*)d_in[7];
  const float* gateB  = (const float*)d_in[8];
  const float* connW  = (const float*)d_in[9];
  const float* lng    = (const float*)d_in[10];
  const float* lnb    = (const float*)d_in[11];
  const float* outW   = (const float*)d_in[12];
  const float* outB   = (const float*)d_in[13];
  const int*   esrc   = (const int*)d_in[14];
  const int*   edst   = (const int*)d_in[15];
  int E = in_sizes[14];
  float* out = (float*)d_out;

  char* ws = (char*)d_ws;
  float* xt     = (float*)(ws + 0);          // 256 KB
  float* scores = (float*)(ws + 262144);     // 256 KB (dead after k_topk)
  // alias worklist into the dead scores region:
  unsigned int* items = (unsigned int*)(ws + 262144);   // E*S*4 <= 131072*... fits in 256KB
  float* wbuf   = (float*)(ws + 524288);     // 52 KB
  int*   active = (int*)  (ws + 589824);     // 6.5 KB
  int*   count  = (int*)  (ws + 596992);     // 4 B (slack before member)
  int*   member = (int*)  (ws + 598016);     // 32 KB
  int*   pos    = (int*)  (ws + 630784);     // 32 KB
  float* states = (float*)(ws + 663552);     // 13.37 MB
  float* nxt    = (float*)(ws + 14032896);   // 13.37 MB
  float* normed = (float*)(ws + 27402240);   // 256 KB

  hipMemsetAsync(nxt, 0, (size_t)3342336 * 4, stream);

  k_embed  <<<dim3(S_ * B_), 256, 0, stream>>>(ids, embed, pose, xt);
  k_router <<<dim3(S_ * B_), 256, 0, stream>>>(xt, rW, rb, scores);
  k_topk   <<<dim3(S_ * B_), 256, 0, stream>>>(scores, wbuf, active, member, pos);
  hipMemsetAsync(count, 0, 4, stream);       // after k_topk: scores region now dead
  k_compact<<<dim3((E * S_ + 255) / 256), 256, 0, stream>>>(esrc, edst, member, E, count, items);
  k_hop0   <<<dim3(K_, S_), 256, 0, stream>>>(xt, fcW, fcB, gateW, gateB, wbuf, active, states);
  k_edge2  <<<dim3(1280), 256, 0, stream>>>(states, connW, fcW, fcB, gateW, gateB,
                                            esrc, edst, pos, count, items, nxt);
  k_ln     <<<dim3(B_ * S_), 256, 0, stream>>>(states, nxt, lng, lnb, normed);
  k_logits <<<dim3((V_ + 511) / 512, 4), 256, 0, stream>>>(normed, outW, outB, out);
}